// Round 5
// baseline (5876.774 us; speedup 1.0000x reference)
//
#include <hip/hip_runtime.h>

#define B_ 128
#define T_ 80
#define AD 32
#define ZD 64
#define KD 16
#define SZ 68   // stride for 64-col LDS matrices (16B-aligned rows)
#define SC 36   // stride for 32-col transposed C / S_ (16B-aligned rows)

__device__ __forceinline__ float4 ld4(const float* p) { return *(const float4*)p; }
__device__ __forceinline__ void st4f(float* p, float4 v) { *(float4*)p = v; }
__device__ __forceinline__ float4 comb2(float a, float4 x, float b, float4 y) {
    return make_float4(a*x.x + b*y.x, a*x.y + b*y.y, a*x.z + b*y.z, a*x.w + b*y.w);
}
__device__ __forceinline__ float4 elim2(float4 c, float g0, float4 x, float g1, float4 y) {
    c.x -= g0*x.x + g1*y.x; c.y -= g0*x.y + g1*y.y;
    c.z -= g0*x.z + g1*y.z; c.w -= g0*x.w + g1*y.w;
    return c;
}

// acc[4][4] += op(A)@B, rows r4..r4+3, cols c4..c4+3.
// A-element A[r][k] = PaT[k*AS + r]  (transposed layout -> b128 reads)
template<int KL, int AS, int BS>
__device__ __forceinline__ void mmT44(const float* __restrict__ PaT, const float* __restrict__ Qb,
                                      float acc[4][4], int r4, int c4)
{
#pragma unroll 8
    for (int k = 0; k < KL; ++k) {
        const float4 av = ld4(&PaT[k*AS + r4]);
        const float4 bv = ld4(&Qb[k*BS + c4]);
        acc[0][0] += av.x*bv.x; acc[0][1] += av.x*bv.y; acc[0][2] += av.x*bv.z; acc[0][3] += av.x*bv.w;
        acc[1][0] += av.y*bv.x; acc[1][1] += av.y*bv.y; acc[1][2] += av.y*bv.z; acc[1][3] += av.y*bv.w;
        acc[2][0] += av.z*bv.x; acc[2][1] += av.z*bv.y; acc[2][2] += av.z*bv.z; acc[2][3] += av.z*bv.w;
        acc[3][0] += av.w*bv.x; acc[3][1] += av.w*bv.y; acc[3][2] += av.w*bv.z; acc[3][3] += av.w*bv.w;
    }
}

__global__ __launch_bounds__(256, 1)
void kvae_kernel(const float* __restrict__ obs, const float* __restrict__ logits,
                 const float* __restrict__ AK, const float* __restrict__ CK,
                 float* __restrict__ out)
{
    __shared__ __align__(16) float W[T_ * KD];
    __shared__ __align__(16) float Am[ZD * SZ];   // A(t+1)
    __shared__ __align__(16) float At[ZD * SZ];   // A(t+1)^T
    __shared__ __align__(16) float SP[ZD * SZ];   // sig_p / spn / V
    __shared__ __align__(16) float SF[ZD * SZ];   // sig_f
    __shared__ __align__(16) float MT[ZD * SZ];   // M^T = SF @ A^T
    __shared__ __align__(16) float Pool[9984];
    __shared__ __align__(16) float pvL[256];      // [2][2][64] published pivot rows (left)
    __shared__ __align__(16) float pvR[256];      // [2][2][64] (right)
    __shared__ __align__(16) float fb[256];       // [2][64][2] per-row multipliers
    __shared__ __align__(16) float pvE[4];        // [2][2] err col
    __shared__ __align__(16) float y_s[32];
    __shared__ __align__(16) float errv[32];
    __shared__ __align__(16) float uev[32];
    __shared__ __align__(16) float mup[64];
    __shared__ __align__(16) float muf[64];
    __shared__ __align__(16) float mus[64];
    __shared__ __align__(16) float mpn[64];
    __shared__ __align__(16) float dv[64];

    // forward aliases in Pool
    float* T1 = Pool;            // [32][68]
    float* CM = Pool + 2176;     // [32][68]
    float* CT = Pool + 4352;     // [64][36]  C^T
    float* S_ = Pool + 6656;     // [32][36]
    float* U_ = Pool + 7808;     // [32][68]  S^-1 T1
    // backward aliases
    float* SG = Pool;            // [64][68]  sig_s carry
    float* Xb = Pool + 4352;     // [64][68]  X = spn^-1 M

    const int tid = threadIdx.x;
    const int b   = blockIdx.x;
    const int cg  = tid & 15;
    const int c4  = cg << 2;           // 0..60
    const int r4  = (tid >> 4) << 2;   // 0..60
    const int r2  = (tid >> 4) << 1;   // 0..30 (32-row stages)
    const int c2  = cg << 1;           // 0..30
    const int gi  = tid >> 2;          // 0..63 GJ64 row
    const int gs  = tid & 3;           // 0..3  GJ64 seg
    const int hi  = tid >> 3;          // 0..31 GJ32 row
    const int hs  = tid & 7;           // 0..7  GJ32 seg

    const float* obs_b = obs    + (size_t)b * T_ * AD;
    const float* lg_b  = logits + (size_t)b * T_ * KD;
    float* omu = out + (size_t)b * T_ * ZD;
    float* osg = out + (size_t)B_ * T_ * ZD + (size_t)b * T_ * ZD * ZD;
    const float4* AK4 = (const float4*)AK;
    const float4* CK4 = (const float4*)CK;

    auto mixA = [&](int tt) {
#pragma unroll
        for (int q = 0; q < 4; q++) {
            const int r = r4 + q;
            float4 a = make_float4(0.f, 0.f, 0.f, 0.f);
#pragma unroll
            for (int k = 0; k < KD; k++) {
                const float wk = W[tt * KD + k];
                const float4 v = AK4[k * 1024 + r * 16 + cg];
                a.x += wk * v.x; a.y += wk * v.y; a.z += wk * v.z; a.w += wk * v.w;
            }
            st4f(&Am[r * SZ + c4], a);
            At[(c4 + 0) * SZ + r] = a.x; At[(c4 + 1) * SZ + r] = a.y;
            At[(c4 + 2) * SZ + r] = a.z; At[(c4 + 3) * SZ + r] = a.w;
        }
    };
    auto mixC = [&](int tt) {
#pragma unroll
        for (int q = 0; q < 2; q++) {
            const int r = r2 + q;
            float4 a = make_float4(0.f, 0.f, 0.f, 0.f);
#pragma unroll
            for (int k = 0; k < KD; k++) {
                const float wk = W[tt * KD + k];
                const float4 v = CK4[k * 512 + r * 16 + cg];
                a.x += wk * v.x; a.y += wk * v.y; a.z += wk * v.z; a.w += wk * v.w;
            }
            st4f(&CM[r * SZ + c4], a);
            CT[(c4 + 0) * SC + r] = a.x; CT[(c4 + 1) * SC + r] = a.y;
            CT[(c4 + 2) * SC + r] = a.z; CT[(c4 + 3) * SC + r] = a.w;
        }
    };

    // ---- prologue
    if (tid < T_) {
        float l[KD]; float mx = -1e30f;
#pragma unroll
        for (int k = 0; k < KD; k++) { l[k] = lg_b[tid * KD + k]; mx = fmaxf(mx, l[k]); }
        float s = 0.f;
#pragma unroll
        for (int k = 0; k < KD; k++) { l[k] = expf(l[k] - mx); s += l[k]; }
        const float inv = 1.0f / s;
#pragma unroll
        for (int k = 0; k < KD; k++) W[tid * KD + k] = l[k] * inv;
    }
#pragma unroll
    for (int q = 0; q < 4; q++) {
        const int r = r4 + q;
#pragma unroll
        for (int j = 0; j < 4; j++) SP[r * SZ + c4 + j] = (r == c4 + j) ? 20.0f : 0.0f;
    }
    if (tid < ZD) mup[tid] = 0.0f;
    __syncthreads();

    // ================= FORWARD FILTER =================
    for (int t = 0; t < T_; t++) {
        // s0: mix A(t+1), C(t); load y
        if (t < T_ - 1) mixA(t + 1);
        mixC(t);
        if (tid < AD) y_s[tid] = obs_b[t * AD + tid];
        __syncthreads();

        // s1: T1 = CM @ SP  [32x64] k=64   (A via CT: b64; B b128)
        {
            float a0[4] = {0,0,0,0}, a1[4] = {0,0,0,0};
#pragma unroll 8
            for (int k = 0; k < ZD; ++k) {
                const float2 av = *(const float2*)&CT[k * SC + r2];
                const float4 bv = ld4(&SP[k * SZ + c4]);
                a0[0] += av.x*bv.x; a0[1] += av.x*bv.y; a0[2] += av.x*bv.z; a0[3] += av.x*bv.w;
                a1[0] += av.y*bv.x; a1[1] += av.y*bv.y; a1[2] += av.y*bv.z; a1[3] += av.y*bv.w;
            }
            st4f(&T1[r2 * SZ + c4], make_float4(a0[0], a0[1], a0[2], a0[3]));
            st4f(&T1[(r2 + 1) * SZ + c4], make_float4(a1[0], a1[1], a1[2], a1[3]));
        }
        __syncthreads();

        // s2: S = T1 @ CM^T + 0.03 I  [32x32] (dot form, 2x2 tile) ; errv = y - CM @ mup
        {
            float s00 = 0, s01 = 0, s10 = 0, s11 = 0;
#pragma unroll 4
            for (int k4 = 0; k4 < ZD; k4 += 4) {
                const float4 t0 = ld4(&T1[r2 * SZ + k4]);
                const float4 t1 = ld4(&T1[(r2 + 1) * SZ + k4]);
                const float4 u0 = ld4(&CM[c2 * SZ + k4]);
                const float4 u1 = ld4(&CM[(c2 + 1) * SZ + k4]);
                s00 += t0.x*u0.x + t0.y*u0.y + t0.z*u0.z + t0.w*u0.w;
                s01 += t0.x*u1.x + t0.y*u1.y + t0.z*u1.z + t0.w*u1.w;
                s10 += t1.x*u0.x + t1.y*u0.y + t1.z*u0.z + t1.w*u0.w;
                s11 += t1.x*u1.x + t1.y*u1.y + t1.z*u1.z + t1.w*u1.w;
            }
            if (r2 == c2) { s00 += 0.03f; s11 += 0.03f; }
            if (r2 + 1 == c2) s10 += 0.03f;
            if (c2 + 1 == r2) s01 += 0.03f;
            S_[r2 * SC + c2] = s00;       S_[r2 * SC + c2 + 1] = s01;
            S_[(r2 + 1) * SC + c2] = s10; S_[(r2 + 1) * SC + c2 + 1] = s11;
        }
        if (tid < AD) {
            float s = 0.f;
#pragma unroll
            for (int k4 = 0; k4 < ZD; k4 += 4) {
                const float4 cm = ld4(&CM[tid * SZ + k4]);
                const float4 mu = ld4(&mup[k4]);
                s += cm.x*mu.x + cm.y*mu.y + cm.z*mu.z + cm.w*mu.w;
            }
            errv[tid] = y_s[tid] - s;
        }
        __syncthreads();

        // ---- GJ32: [S_ | T1, err] -> U_ = S^-1 T1, uev = S^-1 err
        // thread (hi, hs): hs 0-1 left seg, hs 2-5 right seg, hs 6 err, hs 7 idle
        {
            float4 aL0, aL1, aL2, aL3, aR0, aR1, aR2, aR3; float ge = 0.f;
            aL0 = aL1 = aL2 = aL3 = aR0 = aR1 = aR2 = aR3 = make_float4(0, 0, 0, 0);
            if (hs < 2) {
                const float* p = &S_[hi * SC + hs * 16];
                aL0 = ld4(p); aL1 = ld4(p + 4); aL2 = ld4(p + 8); aL3 = ld4(p + 12);
            } else if (hs < 6) {
                const float* p = &T1[hi * SZ + (hs - 2) * 16];
                aR0 = ld4(p); aR1 = ld4(p + 4); aR2 = ld4(p + 8); aR3 = ld4(p + 12);
            } else if (hs == 6) ge = errv[hi];
            if (hi < 2) {
                if (hs < 2) {
                    float* q = &pvL[hi * 64 + hs * 16];
                    st4f(q, aL0); st4f(q + 4, aL1); st4f(q + 8, aL2); st4f(q + 12, aL3);
                } else if (hs < 6) {
                    float* q = &pvR[hi * 64 + (hs - 2) * 16];
                    st4f(q, aR0); st4f(q + 4, aR1); st4f(q + 8, aR2); st4f(q + 12, aR3);
                } else if (hs == 6) pvE[hi] = ge;
            }
            if (hs == 0) { fb[hi * 2] = aL0.x; fb[hi * 2 + 1] = aL0.y; }
            __syncthreads();

#pragma unroll 1
            for (int j8 = 0; j8 < 2; ++j8) {
#pragma unroll
                for (int jj = 0; jj < 8; ++jj) {
                    const int j = j8 * 8 + jj;
                    const int par = j & 1, nb = par ^ 1;
                    const int p0 = 2 * j, p1 = p0 + 1;
                    const float qa = pvL[par * 128 + p0],      qbv = pvL[par * 128 + p1];
                    const float qc = pvL[par * 128 + 64 + p0], qd  = pvL[par * 128 + 64 + p1];
                    const float f0 = fb[par * 128 + hi * 2], f1 = fb[par * 128 + hi * 2 + 1];
                    const float dinv = 1.0f / (qa * qd - qbv * qc);
                    const float i00 = qd * dinv, i01 = -qbv * dinv, i10 = -qc * dinv, i11 = qa * dinv;
                    const float g0 = f0 * i00 + f1 * i10;
                    const float g1 = f0 * i01 + f1 * i11;
                    if (hs < 2) {
                        const float* pl0 = &pvL[par * 128 + hs * 16];
                        const float* pl1 = &pvL[par * 128 + 64 + hs * 16];
                        const float4 x0 = ld4(pl0), x1 = ld4(pl0 + 4), x2 = ld4(pl0 + 8), x3 = ld4(pl0 + 12);
                        const float4 z0 = ld4(pl1), z1 = ld4(pl1 + 4), z2 = ld4(pl1 + 8), z3 = ld4(pl1 + 12);
                        if (hi == p0) {
                            aL0 = comb2(i00, x0, i01, z0); aL1 = comb2(i00, x1, i01, z1);
                            aL2 = comb2(i00, x2, i01, z2); aL3 = comb2(i00, x3, i01, z3);
                        } else if (hi == p1) {
                            aL0 = comb2(i10, x0, i11, z0); aL1 = comb2(i10, x1, i11, z1);
                            aL2 = comb2(i10, x2, i11, z2); aL3 = comb2(i10, x3, i11, z3);
                        } else {
                            aL0 = elim2(aL0, g0, x0, g1, z0); aL1 = elim2(aL1, g0, x1, g1, z1);
                            aL2 = elim2(aL2, g0, x2, g1, z2); aL3 = elim2(aL3, g0, x3, g1, z3);
                        }
                        if (j < 15 && (hi == p0 + 2 || hi == p0 + 3)) {
                            float* q = &pvL[nb * 128 + (hi & 1) * 64 + hs * 16];
                            st4f(q, aL0); st4f(q + 4, aL1); st4f(q + 8, aL2); st4f(q + 12, aL3);
                        }
                    } else if (hs < 6) {
                        const float* pr0 = &pvR[par * 128 + (hs - 2) * 16];
                        const float* pr1 = &pvR[par * 128 + 64 + (hs - 2) * 16];
                        const float4 x0 = ld4(pr0), x1 = ld4(pr0 + 4), x2 = ld4(pr0 + 8), x3 = ld4(pr0 + 12);
                        const float4 z0 = ld4(pr1), z1 = ld4(pr1 + 4), z2 = ld4(pr1 + 8), z3 = ld4(pr1 + 12);
                        if (hi == p0) {
                            aR0 = comb2(i00, x0, i01, z0); aR1 = comb2(i00, x1, i01, z1);
                            aR2 = comb2(i00, x2, i01, z2); aR3 = comb2(i00, x3, i01, z3);
                        } else if (hi == p1) {
                            aR0 = comb2(i10, x0, i11, z0); aR1 = comb2(i10, x1, i11, z1);
                            aR2 = comb2(i10, x2, i11, z2); aR3 = comb2(i10, x3, i11, z3);
                        } else {
                            aR0 = elim2(aR0, g0, x0, g1, z0); aR1 = elim2(aR1, g0, x1, g1, z1);
                            aR2 = elim2(aR2, g0, x2, g1, z2); aR3 = elim2(aR3, g0, x3, g1, z3);
                        }
                        if (j < 15 && (hi == p0 + 2 || hi == p0 + 3)) {
                            float* q = &pvR[nb * 128 + (hi & 1) * 64 + (hs - 2) * 16];
                            st4f(q, aR0); st4f(q + 4, aR1); st4f(q + 8, aR2); st4f(q + 12, aR3);
                        }
                    } else if (hs == 6) {
                        const float e0 = pvE[par * 2], e1 = pvE[par * 2 + 1];
                        const float me0 = i00 * e0 + i01 * e1, me1 = i10 * e0 + i11 * e1;
                        if (hi == p0) ge = me0;
                        else if (hi == p1) ge = me1;
                        else ge -= f0 * me0 + f1 * me1;
                        if (j < 15 && (hi == p0 + 2 || hi == p0 + 3)) pvE[nb * 2 + (hi & 1)] = ge;
                    }
                    if (j < 15 && hs == ((j + 1) >> 3)) {
                        const int pc = (2 * jj + 2) & 15;   // compile-time
                        const float v0 = (pc==0)?aL0.x:(pc==2)?aL0.z:(pc==4)?aL1.x:(pc==6)?aL1.z:
                                         (pc==8)?aL2.x:(pc==10)?aL2.z:(pc==12)?aL3.x:aL3.z;
                        const float v1 = (pc==0)?aL0.y:(pc==2)?aL0.w:(pc==4)?aL1.y:(pc==6)?aL1.w:
                                         (pc==8)?aL2.y:(pc==10)?aL2.w:(pc==12)?aL3.y:aL3.w;
                        fb[nb * 128 + hi * 2] = v0; fb[nb * 128 + hi * 2 + 1] = v1;
                    }
                    __syncthreads();
                }
            }
            if (hs >= 2 && hs < 6) {
                float* q = &U_[hi * SZ + (hs - 2) * 16];
                st4f(q, aR0); st4f(q + 4, aR1); st4f(q + 8, aR2); st4f(q + 12, aR3);
            } else if (hs == 6) uev[hi] = ge;
        }
        __syncthreads();

        // s3: sig_f = SP - T1^T @ U_  -> SF & out ; mu_f = mup + T1^T uev
        {
            float acc[4][4] = {};
            mmT44<AD, SZ, SZ>(T1, U_, acc, r4, c4);
            float* og = osg + (size_t)t * ZD * ZD;
#pragma unroll
            for (int q = 0; q < 4; q++) {
                const int r = r4 + q;
                const float4 sp = ld4(&SP[r * SZ + c4]);
                const float4 v = make_float4(sp.x - acc[q][0], sp.y - acc[q][1],
                                             sp.z - acc[q][2], sp.w - acc[q][3]);
                st4f(&SF[r * SZ + c4], v);
                *(float4*)(og + r * ZD + c4) = v;
            }
        }
        if (tid < ZD) {
            float s = 0.f;
#pragma unroll
            for (int k = 0; k < AD; k++) s += T1[k * SZ + tid] * uev[k];
            const float v = mup[tid] + s;
            muf[tid] = v;
            omu[t * ZD + tid] = v;
        }
        __syncthreads();

        if (t < T_ - 1) {
            // s4: MT = SF @ At  (M^T; SF symmetric so A-op reads SF[k][r] b128)
            {
                float acc[4][4] = {};
                mmT44<ZD, SZ, SZ>(SF, At, acc, r4, c4);
#pragma unroll
                for (int q = 0; q < 4; q++)
                    st4f(&MT[(r4 + q) * SZ + c4],
                         make_float4(acc[q][0], acc[q][1], acc[q][2], acc[q][3]));
            }
            __syncthreads();
            // s5: SP' = MT^T @ At + 0.08 I  (symmetric: upper tiles + mirror)
            if (r4 <= c4) {
                float acc[4][4] = {};
                mmT44<ZD, SZ, SZ>(MT, At, acc, r4, c4);
#pragma unroll
                for (int q = 0; q < 4; q++) {
                    const int r = r4 + q;
#pragma unroll
                    for (int j = 0; j < 4; j++)
                        SP[r * SZ + c4 + j] = acc[q][j] + ((r == c4 + j) ? 0.08f : 0.0f);
                }
            }
            __syncthreads();
            if (r4 > c4) {
                float4 m0 = ld4(&SP[(c4 + 0) * SZ + r4]);
                float4 m1 = ld4(&SP[(c4 + 1) * SZ + r4]);
                float4 m2 = ld4(&SP[(c4 + 2) * SZ + r4]);
                float4 m3 = ld4(&SP[(c4 + 3) * SZ + r4]);
                st4f(&SP[(r4 + 0) * SZ + c4], make_float4(m0.x, m1.x, m2.x, m3.x));
                st4f(&SP[(r4 + 1) * SZ + c4], make_float4(m0.y, m1.y, m2.y, m3.y));
                st4f(&SP[(r4 + 2) * SZ + c4], make_float4(m0.z, m1.z, m2.z, m3.z));
                st4f(&SP[(r4 + 3) * SZ + c4], make_float4(m0.w, m1.w, m2.w, m3.w));
            }
            if (tid < ZD) {
                float s = 0.f;
#pragma unroll
                for (int k4 = 0; k4 < ZD; k4 += 4) {
                    const float4 am = ld4(&Am[tid * SZ + k4]);
                    const float4 mf = ld4(&muf[k4]);
                    s += am.x*mf.x + am.y*mf.y + am.z*mf.z + am.w*mf.w;
                }
                mup[tid] = s;
            }
            __syncthreads();
        }
    }

    // ================= SMOOTHER INIT =================
#pragma unroll
    for (int q = 0; q < 4; q++)
        st4f(&SG[(r4 + q) * SZ + c4], ld4(&SF[(r4 + q) * SZ + c4]));
    if (tid < ZD) mus[tid] = muf[tid];
    __syncthreads();

    // ================= BACKWARD SMOOTHER =================
    for (int t = T_ - 2; t >= 0; t--) {
        // s0: mix A(t+1); load SF(t), muf(t) from out
        mixA(t + 1);
        {
            const float* og = osg + (size_t)t * ZD * ZD;
#pragma unroll
            for (int q = 0; q < 4; q++)
                st4f(&SF[(r4 + q) * SZ + c4], *(const float4*)(og + (r4 + q) * ZD + c4));
        }
        if (tid < ZD) muf[tid] = omu[t * ZD + tid];
        __syncthreads();

        // s1: MT = SF @ At ; mpn = Am @ muf
        {
            float acc[4][4] = {};
            mmT44<ZD, SZ, SZ>(SF, At, acc, r4, c4);
#pragma unroll
            for (int q = 0; q < 4; q++)
                st4f(&MT[(r4 + q) * SZ + c4],
                     make_float4(acc[q][0], acc[q][1], acc[q][2], acc[q][3]));
        }
        if (tid < ZD) {
            float s = 0.f;
#pragma unroll
            for (int k4 = 0; k4 < ZD; k4 += 4) {
                const float4 am = ld4(&Am[tid * SZ + k4]);
                const float4 mf = ld4(&muf[k4]);
                s += am.x*mf.x + am.y*mf.y + am.z*mf.z + am.w*mf.w;
            }
            mpn[tid] = s;
        }
        __syncthreads();

        // s2: spn = MT^T @ At + 0.08 I -> SP (symmetric: upper + mirror) ; dv = mus - mpn
        if (r4 <= c4) {
            float acc[4][4] = {};
            mmT44<ZD, SZ, SZ>(MT, At, acc, r4, c4);
#pragma unroll
            for (int q = 0; q < 4; q++) {
                const int r = r4 + q;
#pragma unroll
                for (int j = 0; j < 4; j++)
                    SP[r * SZ + c4 + j] = acc[q][j] + ((r == c4 + j) ? 0.08f : 0.0f);
            }
        }
        __syncthreads();
        if (r4 > c4) {
            float4 m0 = ld4(&SP[(c4 + 0) * SZ + r4]);
            float4 m1 = ld4(&SP[(c4 + 1) * SZ + r4]);
            float4 m2 = ld4(&SP[(c4 + 2) * SZ + r4]);
            float4 m3 = ld4(&SP[(c4 + 3) * SZ + r4]);
            st4f(&SP[(r4 + 0) * SZ + c4], make_float4(m0.x, m1.x, m2.x, m3.x));
            st4f(&SP[(r4 + 1) * SZ + c4], make_float4(m0.y, m1.y, m2.y, m3.y));
            st4f(&SP[(r4 + 2) * SZ + c4], make_float4(m0.z, m1.z, m2.z, m3.z));
            st4f(&SP[(r4 + 3) * SZ + c4], make_float4(m0.w, m1.w, m2.w, m3.w));
        }
        if (tid < ZD) dv[tid] = mus[tid] - mpn[tid];
        __syncthreads();

        // ---- GJ64: [SP | M] -> Xb = spn^-1 M   (M[i][c] = MT[c][i])
        {
            float4 aL0, aL1, aL2, aL3, aR0, aR1, aR2, aR3;
            {
                const float* p = &SP[gi * SZ + gs * 16];
                aL0 = ld4(p); aL1 = ld4(p + 4); aL2 = ld4(p + 8); aL3 = ld4(p + 12);
                const int cb = gs * 16;
                aR0 = make_float4(MT[(cb+0)*SZ+gi], MT[(cb+1)*SZ+gi], MT[(cb+2)*SZ+gi], MT[(cb+3)*SZ+gi]);
                aR1 = make_float4(MT[(cb+4)*SZ+gi], MT[(cb+5)*SZ+gi], MT[(cb+6)*SZ+gi], MT[(cb+7)*SZ+gi]);
                aR2 = make_float4(MT[(cb+8)*SZ+gi], MT[(cb+9)*SZ+gi], MT[(cb+10)*SZ+gi], MT[(cb+11)*SZ+gi]);
                aR3 = make_float4(MT[(cb+12)*SZ+gi], MT[(cb+13)*SZ+gi], MT[(cb+14)*SZ+gi], MT[(cb+15)*SZ+gi]);
                if (gi < 2) {
                    float* q = &pvL[gi * 64 + gs * 16];
                    st4f(q, aL0); st4f(q + 4, aL1); st4f(q + 8, aL2); st4f(q + 12, aL3);
                    float* q2 = &pvR[gi * 64 + gs * 16];
                    st4f(q2, aR0); st4f(q2 + 4, aR1); st4f(q2 + 8, aR2); st4f(q2 + 12, aR3);
                }
                if (gs == 0) { fb[gi * 2] = aL0.x; fb[gi * 2 + 1] = aL0.y; }
            }
            __syncthreads();

#pragma unroll 1
            for (int j8 = 0; j8 < 4; ++j8) {
#pragma unroll
                for (int jj = 0; jj < 8; ++jj) {
                    const int j = j8 * 8 + jj;
                    const int par = j & 1, nb = par ^ 1;
                    const int p0 = 2 * j, p1 = p0 + 1;
                    const float qa = pvL[par * 128 + p0],      qbv = pvL[par * 128 + p1];
                    const float qc = pvL[par * 128 + 64 + p0], qd  = pvL[par * 128 + 64 + p1];
                    const float f0 = fb[par * 128 + gi * 2], f1 = fb[par * 128 + gi * 2 + 1];
                    const float dinv = 1.0f / (qa * qd - qbv * qc);
                    const float i00 = qd * dinv, i01 = -qbv * dinv, i10 = -qc * dinv, i11 = qa * dinv;
                    const float g0 = f0 * i00 + f1 * i10;
                    const float g1 = f0 * i01 + f1 * i11;
                    const float* pl0 = &pvL[par * 128 + gs * 16];
                    const float* pl1 = &pvL[par * 128 + 64 + gs * 16];
                    const float* pr0 = &pvR[par * 128 + gs * 16];
                    const float* pr1 = &pvR[par * 128 + 64 + gs * 16];
                    const float4 x0 = ld4(pl0), x1 = ld4(pl0 + 4), x2 = ld4(pl0 + 8), x3 = ld4(pl0 + 12);
                    const float4 z0 = ld4(pl1), z1 = ld4(pl1 + 4), z2 = ld4(pl1 + 8), z3 = ld4(pl1 + 12);
                    const float4 u0 = ld4(pr0), u1 = ld4(pr0 + 4), u2 = ld4(pr0 + 8), u3 = ld4(pr0 + 12);
                    const float4 w0 = ld4(pr1), w1 = ld4(pr1 + 4), w2 = ld4(pr1 + 8), w3 = ld4(pr1 + 12);
                    if (gi == p0) {
                        aL0 = comb2(i00, x0, i01, z0); aL1 = comb2(i00, x1, i01, z1);
                        aL2 = comb2(i00, x2, i01, z2); aL3 = comb2(i00, x3, i01, z3);
                        aR0 = comb2(i00, u0, i01, w0); aR1 = comb2(i00, u1, i01, w1);
                        aR2 = comb2(i00, u2, i01, w2); aR3 = comb2(i00, u3, i01, w3);
                    } else if (gi == p1) {
                        aL0 = comb2(i10, x0, i11, z0); aL1 = comb2(i10, x1, i11, z1);
                        aL2 = comb2(i10, x2, i11, z2); aL3 = comb2(i10, x3, i11, z3);
                        aR0 = comb2(i10, u0, i11, w0); aR1 = comb2(i10, u1, i11, w1);
                        aR2 = comb2(i10, u2, i11, w2); aR3 = comb2(i10, u3, i11, w3);
                    } else {
                        aL0 = elim2(aL0, g0, x0, g1, z0); aL1 = elim2(aL1, g0, x1, g1, z1);
                        aL2 = elim2(aL2, g0, x2, g1, z2); aL3 = elim2(aL3, g0, x3, g1, z3);
                        aR0 = elim2(aR0, g0, u0, g1, w0); aR1 = elim2(aR1, g0, u1, g1, w1);
                        aR2 = elim2(aR2, g0, u2, g1, w2); aR3 = elim2(aR3, g0, u3, g1, w3);
                    }
                    if (j < 31 && (gi == p0 + 2 || gi == p0 + 3)) {
                        float* q = &pvL[nb * 128 + (gi & 1) * 64 + gs * 16];
                        st4f(q, aL0); st4f(q + 4, aL1); st4f(q + 8, aL2); st4f(q + 12, aL3);
                        float* q2 = &pvR[nb * 128 + (gi & 1) * 64 + gs * 16];
                        st4f(q2, aR0); st4f(q2 + 4, aR1); st4f(q2 + 8, aR2); st4f(q2 + 12, aR3);
                    }
                    if (j < 31 && gs == ((j + 1) >> 3)) {
                        const int pc = (2 * jj + 2) & 15;   // compile-time
                        const float v0 = (pc==0)?aL0.x:(pc==2)?aL0.z:(pc==4)?aL1.x:(pc==6)?aL1.z:
                                         (pc==8)?aL2.x:(pc==10)?aL2.z:(pc==12)?aL3.x:aL3.z;
                        const float v1 = (pc==0)?aL0.y:(pc==2)?aL0.w:(pc==4)?aL1.y:(pc==6)?aL1.w:
                                         (pc==8)?aL2.y:(pc==10)?aL2.w:(pc==12)?aL3.y:aL3.w;
                        fb[nb * 128 + gi * 2] = v0; fb[nb * 128 + gi * 2 + 1] = v1;
                    }
                    __syncthreads();
                }
            }
            {
                float* q = &Xb[gi * SZ + gs * 16];
                st4f(q, aR0); st4f(q + 4, aR1); st4f(q + 8, aR2); st4f(q + 12, aR3);
            }
        }
        __syncthreads();

        // s3: V = SG @ Xb - M -> SP   (SG symmetric; M[r][c] = MT[c][r])
        {
            float acc[4][4] = {};
            mmT44<ZD, SZ, SZ>(SG, Xb, acc, r4, c4);
            const float4 m0 = ld4(&MT[(c4 + 0) * SZ + r4]);
            const float4 m1 = ld4(&MT[(c4 + 1) * SZ + r4]);
            const float4 m2 = ld4(&MT[(c4 + 2) * SZ + r4]);
            const float4 m3 = ld4(&MT[(c4 + 3) * SZ + r4]);
            acc[0][0] -= m0.x; acc[0][1] -= m1.x; acc[0][2] -= m2.x; acc[0][3] -= m3.x;
            acc[1][0] -= m0.y; acc[1][1] -= m1.y; acc[1][2] -= m2.y; acc[1][3] -= m3.y;
            acc[2][0] -= m0.z; acc[2][1] -= m1.z; acc[2][2] -= m2.z; acc[2][3] -= m3.z;
            acc[3][0] -= m0.w; acc[3][1] -= m1.w; acc[3][2] -= m2.w; acc[3][3] -= m3.w;
            __syncthreads();   // SP (spn) dead only after GJ; safe to overwrite now
#pragma unroll
            for (int q = 0; q < 4; q++)
                st4f(&SP[(r4 + q) * SZ + c4],
                     make_float4(acc[q][0], acc[q][1], acc[q][2], acc[q][3]));
        }
        __syncthreads();

        // s4: sig_s = SF + Xb^T @ SP -> SG & out ; mu_s = muf + Xb^T dv
        {
            float acc[4][4] = {};
            mmT44<ZD, SZ, SZ>(Xb, SP, acc, r4, c4);
            float* og = osg + (size_t)t * ZD * ZD;
#pragma unroll
            for (int q = 0; q < 4; q++) {
                const int r = r4 + q;
                const float4 sf = ld4(&SF[r * SZ + c4]);
                const float4 v = make_float4(sf.x + acc[q][0], sf.y + acc[q][1],
                                             sf.z + acc[q][2], sf.w + acc[q][3]);
                st4f(&SG[r * SZ + c4], v);
                *(float4*)(og + r * ZD + c4) = v;
            }
        }
        if (tid < ZD) {
            float s = 0.f;
#pragma unroll
            for (int k = 0; k < ZD; k++) s += Xb[k * SZ + tid] * dv[k];
            const float v = muf[tid] + s;
            mus[tid] = v;
            omu[t * ZD + tid] = v;
        }
        __syncthreads();
    }
}

extern "C" void kernel_launch(void* const* d_in, const int* in_sizes, int n_in,
                              void* d_out, int out_size, void* d_ws, size_t ws_size,
                              hipStream_t stream) {
    const float* obs = (const float*)d_in[0];
    const float* lg  = (const float*)d_in[1];
    const float* AK  = (const float*)d_in[2];
    const float* CK  = (const float*)d_in[3];
    (void)d_ws; (void)ws_size; (void)in_sizes; (void)n_in; (void)out_size;
    kvae_kernel<<<dim3(B_), dim3(256), 0, stream>>>(obs, lg, AK, CK, (float*)d_out);
}

// Round 6
// 3609.455 us; speedup vs baseline: 1.6282x; 1.6282x over previous
//
#include <hip/hip_runtime.h>

#define B_ 128
#define T_ 80
#define AD 32
#define ZD 64
#define KD 16
#define S8 68   // stride for 64-col LDS matrices (16B-aligned rows)
#define SC 36   // stride for 32-col matrices (16B-aligned rows)

__device__ __forceinline__ float4 ld4(const float* p) { return *(const float4*)p; }
__device__ __forceinline__ void st4f(float* p, float4 v) { *(float4*)p = v; }

// component-wise: c.x*x0 + c.y*x1 + c.z*x2 + c.w*x3
__device__ __forceinline__ float4 comb4(float4 c, float4 x0, float4 x1, float4 x2, float4 x3) {
    return make_float4(c.x*x0.x + c.y*x1.x + c.z*x2.x + c.w*x3.x,
                       c.x*x0.y + c.y*x1.y + c.z*x2.y + c.w*x3.y,
                       c.x*x0.z + c.y*x1.z + c.z*x2.z + c.w*x3.z,
                       c.x*x0.w + c.y*x1.w + c.z*x2.w + c.w*x3.w);
}

// 4x4 inverse via 2x2-block Schur (SPD principal block -> no pivoting needed).
__device__ __forceinline__ void pinv4(float4 q0, float4 q1, float4 q2, float4 q3,
                                      float4& pi0, float4& pi1, float4& pi2, float4& pi3)
{
    const float ra = 1.0f / (q0.x*q1.y - q0.y*q1.x);
    const float ai00 =  q1.y*ra, ai01 = -q0.y*ra, ai10 = -q1.x*ra, ai11 = q0.x*ra;
    const float ca00 = q2.x*ai00 + q2.y*ai10, ca01 = q2.x*ai01 + q2.y*ai11;
    const float ca10 = q3.x*ai00 + q3.y*ai10, ca11 = q3.x*ai01 + q3.y*ai11;
    const float s00 = q2.z - (ca00*q0.z + ca01*q1.z), s01 = q2.w - (ca00*q0.w + ca01*q1.w);
    const float s10 = q3.z - (ca10*q0.z + ca11*q1.z), s11 = q3.w - (ca10*q0.w + ca11*q1.w);
    const float rs = 1.0f / (s00*s11 - s01*s10);
    const float si00 = s11*rs, si01 = -s01*rs, si10 = -s10*rs, si11 = s00*rs;
    const float ab00 = ai00*q0.z + ai01*q1.z, ab01 = ai00*q0.w + ai01*q1.w;
    const float ab10 = ai10*q0.z + ai11*q1.z, ab11 = ai10*q0.w + ai11*q1.w;
    const float t00 = ab00*si00 + ab01*si10, t01 = ab00*si01 + ab01*si11;
    const float t10 = ab10*si00 + ab11*si10, t11 = ab10*si01 + ab11*si11;
    const float tl00 = ai00 + (t00*ca00 + t01*ca10), tl01 = ai01 + (t00*ca01 + t01*ca11);
    const float tl10 = ai10 + (t10*ca00 + t11*ca10), tl11 = ai11 + (t10*ca01 + t11*ca11);
    const float bl00 = -(si00*ca00 + si01*ca10), bl01 = -(si00*ca01 + si01*ca11);
    const float bl10 = -(si10*ca00 + si11*ca10), bl11 = -(si10*ca01 + si11*ca11);
    pi0 = make_float4(tl00, tl01, -t00, -t01);
    pi1 = make_float4(tl10, tl11, -t10, -t11);
    pi2 = make_float4(bl00, bl01, si00, si01);
    pi3 = make_float4(bl10, bl11, si10, si11);
}

// acc[2][4] += op(Pa) @ Qb for rows (r2,r2+1), cols c4..c4+3.
template<int KL, int AS, int BS, bool ATRANS>
__device__ __forceinline__ void mm64(const float* __restrict__ Pa, const float* __restrict__ Qb,
                                     float acc[2][4], int r2, int c4)
{
#pragma unroll 8
    for (int k = 0; k < KL; k++) {
        float aA, aB;
        if (ATRANS) { aA = Pa[k * AS + r2];   aB = Pa[k * AS + r2 + 1]; }
        else        { aA = Pa[r2 * AS + k];   aB = Pa[(r2 + 1) * AS + k]; }
        const float4 bv = ld4(&Qb[k * BS + c4]);
        acc[0][0] += aA * bv.x; acc[0][1] += aA * bv.y; acc[0][2] += aA * bv.z; acc[0][3] += aA * bv.w;
        acc[1][0] += aB * bv.x; acc[1][1] += aB * bv.y; acc[1][2] += aB * bv.z; acc[1][3] += aB * bv.w;
    }
}

__global__ __launch_bounds__(512, 2)
void kvae_kernel(const float* __restrict__ obs, const float* __restrict__ logits,
                 const float* __restrict__ AK, const float* __restrict__ CK,
                 float* __restrict__ out)
{
    __shared__ __align__(16) float W[T_ * KD];
    __shared__ __align__(16) float Am[ZD * S8];   // A(t+1)
    __shared__ __align__(16) float At[ZD * S8];   // A(t+1)^T
    __shared__ __align__(16) float SP[ZD * S8];   // sig_p / spn / V
    __shared__ __align__(16) float SF[ZD * S8];   // sig_f
    __shared__ __align__(16) float Mm[ZD * S8];   // M
    __shared__ __align__(16) float Pool[9984];
    __shared__ __align__(16) float pvL[512];      // published pivot rows, left  [2][4][*]
    __shared__ __align__(16) float pvR[512];      // published pivot rows, right [2][4][*]
    __shared__ __align__(16) float fbb[512];      // per-row multiplier quads [2][rows][4]
    __shared__ __align__(16) float pvE[8];        // err col pivot values [2][4]
    __shared__ __align__(16) float y_s[32];
    __shared__ __align__(16) float errv[32];
    __shared__ __align__(16) float uev[32];
    __shared__ __align__(16) float mup[64];
    __shared__ __align__(16) float muf[64];
    __shared__ __align__(16) float mus[64];
    __shared__ __align__(16) float mpn[64];
    __shared__ __align__(16) float dv[64];

    // forward aliases
    float* T1 = Pool;            // [32][68]
    float* CM = Pool + 2176;     // [32][68]
    float* CT = Pool + 4352;     // [64][36]  C^T
    float* U_ = Pool + 6656;     // [32][68]  S^-1 T1
    float* S_ = Pool + 8832;     // [32][36]
    // backward aliases
    float* Xb = Pool;            // [64][68]  X = spn^-1 M
    float* SG = Pool + 4352;     // [64][68]  sig_s carry

    const int tid = threadIdx.x;
    const int b   = blockIdx.x;

    const int r16 = tid >> 4;       // 0..31
    const int cg  = tid & 15;       // 0..15
    const int c4  = cg << 2;        // 0..60
    const int c2  = cg << 1;        // 0..30
    const int r2  = r16 << 1;       // 0..62
    const int gi  = tid >> 3;       // 0..63  GJ64 row
    const int gs  = tid & 7;        // 0..7   GJ64 seg (8 cols)

    const float* obs_b = obs    + (size_t)b * T_ * AD;
    const float* lg_b  = logits + (size_t)b * T_ * KD;
    float* omu = out + (size_t)b * T_ * ZD;
    float* osg = out + (size_t)B_ * T_ * ZD + (size_t)b * T_ * ZD * ZD;
    const float4* AK4 = (const float4*)AK;
    const float4* CK4 = (const float4*)CK;

    auto mixA = [&](int tt) {
#pragma unroll
        for (int rr = 0; rr < 2; rr++) {
            const int r = r2 + rr;
            float4 a = make_float4(0.f, 0.f, 0.f, 0.f);
#pragma unroll
            for (int k = 0; k < KD; k++) {
                const float wk = W[tt * KD + k];
                const float4 v = AK4[k * 1024 + r * 16 + cg];
                a.x += wk * v.x; a.y += wk * v.y; a.z += wk * v.z; a.w += wk * v.w;
            }
            st4f(&Am[r * S8 + c4], a);
            At[(c4 + 0) * S8 + r] = a.x; At[(c4 + 1) * S8 + r] = a.y;
            At[(c4 + 2) * S8 + r] = a.z; At[(c4 + 3) * S8 + r] = a.w;
        }
    };
    auto mixC = [&](int tt) {
        float4 a = make_float4(0.f, 0.f, 0.f, 0.f);
#pragma unroll
        for (int k = 0; k < KD; k++) {
            const float wk = W[tt * KD + k];
            const float4 v = CK4[k * 512 + r16 * 16 + cg];
            a.x += wk * v.x; a.y += wk * v.y; a.z += wk * v.z; a.w += wk * v.w;
        }
        st4f(&CM[r16 * S8 + c4], a);
        CT[(c4 + 0) * SC + r16] = a.x; CT[(c4 + 1) * SC + r16] = a.y;
        CT[(c4 + 2) * SC + r16] = a.z; CT[(c4 + 3) * SC + r16] = a.w;
    };

    // ---- prologue
    if (tid < T_) {
        float l[KD]; float mx = -1e30f;
#pragma unroll
        for (int k = 0; k < KD; k++) { l[k] = lg_b[tid * KD + k]; mx = fmaxf(mx, l[k]); }
        float s = 0.f;
#pragma unroll
        for (int k = 0; k < KD; k++) { l[k] = expf(l[k] - mx); s += l[k]; }
        const float inv = 1.0f / s;
#pragma unroll
        for (int k = 0; k < KD; k++) W[tid * KD + k] = l[k] * inv;
    }
#pragma unroll
    for (int rr = 0; rr < 2; rr++) {
        const int r = r2 + rr;
#pragma unroll
        for (int j = 0; j < 4; j++) SP[r * S8 + c4 + j] = (r == c4 + j) ? 20.0f : 0.0f;
    }
    if (tid < ZD) mup[tid] = 0.0f;
    __syncthreads();

    // ================= FORWARD FILTER =================
    for (int t = 0; t < T_; t++) {
        // s0: mix A(t+1), C(t); load y
        if (t < T_ - 1) mixA(t + 1);
        mixC(t);
        if (tid < AD) y_s[tid] = obs_b[t * AD + tid];
        __syncthreads();

        // s1: T1 = CM @ SP  [32x64] k=64
        {
            float a0 = 0, a1 = 0, a2 = 0, a3 = 0;
            const float* pa = CM + r16 * S8;
#pragma unroll 8
            for (int k = 0; k < ZD; k++) {
                const float a = pa[k];
                const float4 bv = ld4(&SP[k * S8 + c4]);
                a0 += a * bv.x; a1 += a * bv.y; a2 += a * bv.z; a3 += a * bv.w;
            }
            T1[r16 * S8 + c4 + 0] = a0; T1[r16 * S8 + c4 + 1] = a1;
            T1[r16 * S8 + c4 + 2] = a2; T1[r16 * S8 + c4 + 3] = a3;
        }
        __syncthreads();

        // s2: S = T1 @ CT + 0.03 I ; errv = y - CM @ mup
        {
            float a0 = 0, a1 = 0;
            const float* pa = T1 + r16 * S8;
#pragma unroll 8
            for (int k = 0; k < ZD; k++) {
                const float a = pa[k];
                const float2 bv = *(const float2*)&CT[k * SC + c2];
                a0 += a * bv.x; a1 += a * bv.y;
            }
            if (r16 == c2)     a0 += 0.03f;
            if (r16 == c2 + 1) a1 += 0.03f;
            S_[r16 * SC + c2] = a0; S_[r16 * SC + c2 + 1] = a1;
        }
        if (tid < AD) {
            float s = 0.f;
#pragma unroll
            for (int k4 = 0; k4 < ZD; k4 += 4) {
                const float4 cm = ld4(&CM[tid * S8 + k4]);
                const float4 mu = ld4(&mup[k4]);
                s += cm.x*mu.x + cm.y*mu.y + cm.z*mu.z + cm.w*mu.w;
            }
            errv[tid] = y_s[tid] - s;
        }
        __syncthreads();

        // ---- GJ32: [S_ | T1, errv] -> U_ = S^-1 T1, uev = S^-1 err
        // thread (hi=r16, hs=cg): left f4 at hs*4 (hs<8), right f4 at hs*4 (all), err (hs==15)
        {
            const int hi = r16, hs = cg;
            float4 aL = make_float4(0, 0, 0, 0);
            float4 aR = ld4(&T1[hi * S8 + hs * 4]);
            float e = 0.f;
            if (hs < 8) aL = ld4(&S_[hi * SC + hs * 4]);
            if (hs == 15) e = errv[hi];
            if (hi < 4) {
                if (hs < 8) st4f(&pvL[hi * 32 + hs * 4], aL);
                st4f(&pvR[hi * 64 + hs * 4], aR);
                if (hs == 15) pvE[hi] = e;
            }
            if (hs == 0) st4f(&fbb[hi * 4], aL);
            __syncthreads();

#pragma unroll 2
            for (int j = 0; j < 8; ++j) {
                const int par = j & 1, nb = par ^ 1;
                const bool isp = (hi >> 2) == j;
                const float4 f  = ld4(&fbb[par * 128 + hi * 4]);
                const float4 q0 = ld4(&fbb[par * 128 + (4 * j + 0) * 4]);
                const float4 q1 = ld4(&fbb[par * 128 + (4 * j + 1) * 4]);
                const float4 q2 = ld4(&fbb[par * 128 + (4 * j + 2) * 4]);
                const float4 q3 = ld4(&fbb[par * 128 + (4 * j + 3) * 4]);
                float4 pi0, pi1, pi2, pi3;
                pinv4(q0, q1, q2, q3, pi0, pi1, pi2, pi3);
                const int rr = hi & 3;
                const float4 coef = isp ? (rr == 0 ? pi0 : rr == 1 ? pi1 : rr == 2 ? pi2 : pi3)
                                        : comb4(f, pi0, pi1, pi2, pi3);
                // right
                {
                    const float4 x0 = ld4(&pvR[par * 256 + 0 * 64 + hs * 4]);
                    const float4 x1 = ld4(&pvR[par * 256 + 1 * 64 + hs * 4]);
                    const float4 x2 = ld4(&pvR[par * 256 + 2 * 64 + hs * 4]);
                    const float4 x3 = ld4(&pvR[par * 256 + 3 * 64 + hs * 4]);
                    const float4 c = comb4(coef, x0, x1, x2, x3);
                    if (isp) aR = c;
                    else { aR.x -= c.x; aR.y -= c.y; aR.z -= c.z; aR.w -= c.w; }
                }
                // left
                if (hs < 8) {
                    const float4 x0 = ld4(&pvL[par * 128 + 0 * 32 + hs * 4]);
                    const float4 x1 = ld4(&pvL[par * 128 + 1 * 32 + hs * 4]);
                    const float4 x2 = ld4(&pvL[par * 128 + 2 * 32 + hs * 4]);
                    const float4 x3 = ld4(&pvL[par * 128 + 3 * 32 + hs * 4]);
                    const float4 c = comb4(coef, x0, x1, x2, x3);
                    if (isp) aL = c;
                    else { aL.x -= c.x; aL.y -= c.y; aL.z -= c.z; aL.w -= c.w; }
                }
                // err
                if (hs == 15) {
                    const float e0 = pvE[par * 4 + 0], e1 = pvE[par * 4 + 1];
                    const float e2 = pvE[par * 4 + 2], e3 = pvE[par * 4 + 3];
                    const float ce = coef.x * e0 + coef.y * e1 + coef.z * e2 + coef.w * e3;
                    if (isp) e = ce; else e -= ce;
                }
                if (j < 7) {
                    if ((hi >> 2) == j + 1) {
                        if (hs < 8) st4f(&pvL[nb * 128 + (hi & 3) * 32 + hs * 4], aL);
                        st4f(&pvR[nb * 256 + (hi & 3) * 64 + hs * 4], aR);
                        if (hs == 15) pvE[nb * 4 + (hi & 3)] = e;
                    }
                    if (hs == j + 1) st4f(&fbb[nb * 128 + hi * 4], aL);
                }
                __syncthreads();
            }
            st4f(&U_[hi * S8 + hs * 4], aR);
            if (hs == 15) uev[hi] = e;
        }
        __syncthreads();

        // s3: sig_f = SP - T1^T U_ -> SF & out ; mu_f = mup + T1^T uev
        {
            float acc[2][4] = {};
            mm64<AD, S8, S8, true>(T1, U_, acc, r2, c4);
            float* og = osg + (size_t)t * ZD * ZD;
#pragma unroll
            for (int rr = 0; rr < 2; rr++) {
                const int r = r2 + rr;
                const float4 sp = ld4(&SP[r * S8 + c4]);
                const float4 v = make_float4(sp.x - acc[rr][0], sp.y - acc[rr][1],
                                             sp.z - acc[rr][2], sp.w - acc[rr][3]);
                st4f(&SF[r * S8 + c4], v);
                *(float4*)(og + r * ZD + c4) = v;
            }
        }
        if (tid < ZD) {
            float s = 0.f;
#pragma unroll
            for (int k = 0; k < AD; k++) s += T1[k * S8 + tid] * uev[k];
            const float v = mup[tid] + s;
            muf[tid] = v;
            omu[t * ZD + tid] = v;
        }
        __syncthreads();

        if (t < T_ - 1) {
            // s4: M = A(t+1) @ SF
            {
                float acc[2][4] = {};
                mm64<ZD, S8, S8, false>(Am, SF, acc, r2, c4);
#pragma unroll
                for (int rr = 0; rr < 2; rr++)
                    st4f(&Mm[(r2 + rr) * S8 + c4],
                         make_float4(acc[rr][0], acc[rr][1], acc[rr][2], acc[rr][3]));
            }
            __syncthreads();
            // s5: SP' = M @ A^T + Q ; mup' = A(t+1) @ muf
            {
                float acc[2][4] = {};
                mm64<ZD, S8, S8, false>(Mm, At, acc, r2, c4);
#pragma unroll
                for (int rr = 0; rr < 2; rr++) {
                    const int r = r2 + rr;
#pragma unroll
                    for (int j = 0; j < 4; j++)
                        SP[r * S8 + c4 + j] = acc[rr][j] + ((r == c4 + j) ? 0.08f : 0.0f);
                }
            }
            if (tid >= 448) {
                const int i = tid - 448;
                float s = 0.f;
                const float* pa = Am + i * S8;
#pragma unroll 8
                for (int k = 0; k < ZD; k++) s += pa[k] * muf[k];
                mup[i] = s;
            }
            __syncthreads();
        }
    }

    // ================= SMOOTHER INIT =================
#pragma unroll
    for (int rr = 0; rr < 2; rr++)
        st4f(&SG[(r2 + rr) * S8 + c4], ld4(&SF[(r2 + rr) * S8 + c4]));
    if (tid < ZD) mus[tid] = muf[tid];
    __syncthreads();

    // ================= BACKWARD SMOOTHER =================
    for (int t = T_ - 2; t >= 0; t--) {
        // s0: mix A(t+1); load SF(t), muf(t) from out
        mixA(t + 1);
        {
            const float4* og4 = (const float4*)(osg + (size_t)t * ZD * ZD);
#pragma unroll
            for (int rr = 0; rr < 2; rr++)
                st4f(&SF[(r2 + rr) * S8 + c4], og4[(r2 + rr) * 16 + cg]);
        }
        if (tid >= 448) muf[tid - 448] = omu[t * ZD + (tid - 448)];
        __syncthreads();

        // s1: M = A(t+1) @ SF -> Mm ; mpn = A @ muf
        {
            float acc[2][4] = {};
            mm64<ZD, S8, S8, false>(Am, SF, acc, r2, c4);
#pragma unroll
            for (int rr = 0; rr < 2; rr++)
                st4f(&Mm[(r2 + rr) * S8 + c4],
                     make_float4(acc[rr][0], acc[rr][1], acc[rr][2], acc[rr][3]));
        }
        if (tid >= 448) {
            const int i = tid - 448;
            float s = 0.f;
            const float* pa = Am + i * S8;
#pragma unroll 8
            for (int k = 0; k < ZD; k++) s += pa[k] * muf[k];
            mpn[i] = s;
        }
        __syncthreads();

        // s2: spn = M @ A^T + Q -> SP ; dv = mus - mpn
        {
            float acc[2][4] = {};
            mm64<ZD, S8, S8, false>(Mm, At, acc, r2, c4);
#pragma unroll
            for (int rr = 0; rr < 2; rr++) {
                const int r = r2 + rr;
#pragma unroll
                for (int j = 0; j < 4; j++)
                    SP[r * S8 + c4 + j] = acc[rr][j] + ((r == c4 + j) ? 0.08f : 0.0f);
            }
        }
        if (tid >= 448) { const int i = tid - 448; dv[i] = mus[i] - mpn[i]; }
        __syncthreads();

        // ---- GJ64: [SP | Mm] -> Xb = spn^-1 M  (register rows, 16 steps, 1 barrier each)
        {
            float4 aL0 = ld4(&SP[gi * S8 + gs * 8]);
            float4 aL1 = ld4(&SP[gi * S8 + gs * 8 + 4]);
            float4 aR0 = ld4(&Mm[gi * S8 + gs * 8]);
            float4 aR1 = ld4(&Mm[gi * S8 + gs * 8 + 4]);
            if (gi < 4) {
                st4f(&pvL[gi * 64 + gs * 8], aL0); st4f(&pvL[gi * 64 + gs * 8 + 4], aL1);
                st4f(&pvR[gi * 64 + gs * 8], aR0); st4f(&pvR[gi * 64 + gs * 8 + 4], aR1);
            }
            if (gs == 0) st4f(&fbb[gi * 4], aL0);
            __syncthreads();

#pragma unroll 2
            for (int j = 0; j < 16; ++j) {
                const int par = j & 1, nb = par ^ 1;
                const bool isp = (gi >> 2) == j;
                const float4 f  = ld4(&fbb[par * 256 + gi * 4]);
                const float4 q0 = ld4(&fbb[par * 256 + (4 * j + 0) * 4]);
                const float4 q1 = ld4(&fbb[par * 256 + (4 * j + 1) * 4]);
                const float4 q2 = ld4(&fbb[par * 256 + (4 * j + 2) * 4]);
                const float4 q3 = ld4(&fbb[par * 256 + (4 * j + 3) * 4]);
                float4 pi0, pi1, pi2, pi3;
                pinv4(q0, q1, q2, q3, pi0, pi1, pi2, pi3);
                const int rr = gi & 3;
                const float4 coef = isp ? (rr == 0 ? pi0 : rr == 1 ? pi1 : rr == 2 ? pi2 : pi3)
                                        : comb4(f, pi0, pi1, pi2, pi3);
                // left halves
                {
                    const float4 x0 = ld4(&pvL[par * 256 + 0 * 64 + gs * 8]);
                    const float4 x1 = ld4(&pvL[par * 256 + 1 * 64 + gs * 8]);
                    const float4 x2 = ld4(&pvL[par * 256 + 2 * 64 + gs * 8]);
                    const float4 x3 = ld4(&pvL[par * 256 + 3 * 64 + gs * 8]);
                    const float4 c = comb4(coef, x0, x1, x2, x3);
                    if (isp) aL0 = c;
                    else { aL0.x -= c.x; aL0.y -= c.y; aL0.z -= c.z; aL0.w -= c.w; }
                }
                {
                    const float4 x0 = ld4(&pvL[par * 256 + 0 * 64 + gs * 8 + 4]);
                    const float4 x1 = ld4(&pvL[par * 256 + 1 * 64 + gs * 8 + 4]);
                    const float4 x2 = ld4(&pvL[par * 256 + 2 * 64 + gs * 8 + 4]);
                    const float4 x3 = ld4(&pvL[par * 256 + 3 * 64 + gs * 8 + 4]);
                    const float4 c = comb4(coef, x0, x1, x2, x3);
                    if (isp) aL1 = c;
                    else { aL1.x -= c.x; aL1.y -= c.y; aL1.z -= c.z; aL1.w -= c.w; }
                }
                // right halves
                {
                    const float4 x0 = ld4(&pvR[par * 256 + 0 * 64 + gs * 8]);
                    const float4 x1 = ld4(&pvR[par * 256 + 1 * 64 + gs * 8]);
                    const float4 x2 = ld4(&pvR[par * 256 + 2 * 64 + gs * 8]);
                    const float4 x3 = ld4(&pvR[par * 256 + 3 * 64 + gs * 8]);
                    const float4 c = comb4(coef, x0, x1, x2, x3);
                    if (isp) aR0 = c;
                    else { aR0.x -= c.x; aR0.y -= c.y; aR0.z -= c.z; aR0.w -= c.w; }
                }
                {
                    const float4 x0 = ld4(&pvR[par * 256 + 0 * 64 + gs * 8 + 4]);
                    const float4 x1 = ld4(&pvR[par * 256 + 1 * 64 + gs * 8 + 4]);
                    const float4 x2 = ld4(&pvR[par * 256 + 2 * 64 + gs * 8 + 4]);
                    const float4 x3 = ld4(&pvR[par * 256 + 3 * 64 + gs * 8 + 4]);
                    const float4 c = comb4(coef, x0, x1, x2, x3);
                    if (isp) aR1 = c;
                    else { aR1.x -= c.x; aR1.y -= c.y; aR1.z -= c.z; aR1.w -= c.w; }
                }
                if (j < 15) {
                    if ((gi >> 2) == j + 1) {
                        const int rn = gi & 3;
                        st4f(&pvL[nb * 256 + rn * 64 + gs * 8], aL0);
                        st4f(&pvL[nb * 256 + rn * 64 + gs * 8 + 4], aL1);
                        st4f(&pvR[nb * 256 + rn * 64 + gs * 8], aR0);
                        st4f(&pvR[nb * 256 + rn * 64 + gs * 8 + 4], aR1);
                    }
                    if (gs == ((j + 1) >> 1))
                        st4f(&fbb[nb * 256 + gi * 4], ((j + 1) & 1) ? aL1 : aL0);
                }
                __syncthreads();
            }
            st4f(&Xb[gi * S8 + gs * 8], aR0);
            st4f(&Xb[gi * S8 + gs * 8 + 4], aR1);
        }
        __syncthreads();

        // s3: V = SG @ Xb - M -> SP
        {
            float acc[2][4] = {};
            mm64<ZD, S8, S8, false>(SG, Xb, acc, r2, c4);
#pragma unroll
            for (int rr = 0; rr < 2; rr++) {
                const int r = r2 + rr;
                const float4 m = ld4(&Mm[r * S8 + c4]);
                SP[r * S8 + c4 + 0] = acc[rr][0] - m.x;
                SP[r * S8 + c4 + 1] = acc[rr][1] - m.y;
                SP[r * S8 + c4 + 2] = acc[rr][2] - m.z;
                SP[r * S8 + c4 + 3] = acc[rr][3] - m.w;
            }
        }
        __syncthreads();

        // s4: sig_s = SF + Xb^T @ SP -> SG & out ; mu_s = muf + Xb^T dv
        {
            float acc[2][4] = {};
            mm64<ZD, S8, S8, true>(Xb, SP, acc, r2, c4);
            float* og = osg + (size_t)t * ZD * ZD;
#pragma unroll
            for (int rr = 0; rr < 2; rr++) {
                const int r = r2 + rr;
                const float4 sf = ld4(&SF[r * S8 + c4]);
                const float4 v = make_float4(sf.x + acc[rr][0], sf.y + acc[rr][1],
                                             sf.z + acc[rr][2], sf.w + acc[rr][3]);
                st4f(&SG[r * S8 + c4], v);
                *(float4*)(og + r * ZD + c4) = v;
            }
        }
        if (tid < ZD) {
            float s = 0.f;
#pragma unroll 8
            for (int k = 0; k < ZD; k++) s += Xb[k * S8 + tid] * dv[k];
            const float v = muf[tid] + s;
            mus[tid] = v;
            omu[t * ZD + tid] = v;
        }
        __syncthreads();
    }
}

extern "C" void kernel_launch(void* const* d_in, const int* in_sizes, int n_in,
                              void* d_out, int out_size, void* d_ws, size_t ws_size,
                              hipStream_t stream) {
    const float* obs = (const float*)d_in[0];
    const float* lg  = (const float*)d_in[1];
    const float* AK  = (const float*)d_in[2];
    const float* CK  = (const float*)d_in[3];
    (void)d_ws; (void)ws_size; (void)in_sizes; (void)n_in; (void)out_size;
    kvae_kernel<<<dim3(B_), dim3(512), 0, stream>>>(obs, lg, AK, CK, (float*)d_out);
}